// Round 5
// baseline (241.380 us; speedup 1.0000x reference)
//
#include <hip/hip_runtime.h>

// Soft decision tree DEPTH=8, 255 internal nodes (heap order), 256 leaves,
// 10 classes, B=131072, 32 feats. fp32 in/out.
//
// R5: attack the remaining DS-latency stalls (R4 = 86us, ~3x over DS
// throughput):
//  - Leaf accumulation via unsafeAtomicAdd -> native ds_add_f32
//    (fire-and-forget: no return value, no lgkm wait, no CAS loop, no RAW
//    chain). R2's 183us atomicAdd was the CAS lowering; unsafe variant is
//    the native one. Slots row-indexed (shared by the 4 row-threads; atomic).
//  - FOUR threads per row (h = t>>6 picks 2 of the 8 depth-3 subtrees;
//    +5 duplicated top evals/row = +2% work): 8192 waves -> 8 waves/SIMD,
//    per-thread DS ops 512 -> 194, LDS 13.8 KB -> 8 blocks/CU (grid 2048).
// Unchanged: pure-DS hot loop, packed node records (b64 depth 0..6 /
// b128 depth 7 incl. both leaf classes), transposed conflict-free s_xT
// pre-scaled by log2e, fully-inlined DFS, exp2-based sigmoid.
// LDS/block = 1016 + 2048 + 8192 + 2560 = 13816 B.

#define NFEAT 32
#define NCLS  10
#define TPB   256
#define RPB   64           // rows per block (4 threads per row)
#define L2E   1.4426950408889634f

__device__ __forceinline__ float fexp2(float z) {
#if __has_builtin(__builtin_amdgcn_exp2f)
  return __builtin_amdgcn_exp2f(z);   // raw v_exp_f32
#else
  return exp2f(z);
#endif
}
__device__ __forceinline__ float frcp(float z) {
#if __has_builtin(__builtin_amdgcn_rcpf)
  return __builtin_amdgcn_rcpf(z);    // raw v_rcp_f32
#else
  return 1.0f / z;
#endif
}

// sigmoid(x-t): e = exp2(t2 - x2); act = 1/(1+e); 1-act = e*act
__device__ __forceinline__ void evaln(const int2* nd, const float* xT,
                                      int n, int row, float p,
                                      float& pl, float& pr) {
  const int2 r = nd[n];                        // ds_read_b64 broadcast, static addr
  const float x2 = xT[(r.y << 6) + row];       // ds_read_b32, lane-linear
  const float e = fexp2(__int_as_float(r.x) - x2);
  const float a = frcp(1.0f + e);
  pr = p * a;
  pl = pr * e;
}

template <int D>
__device__ __forceinline__ void dfs(const int2* nd, const int4* nd7,
                                    const float* xT, float* acc,
                                    int n, int row, float p) {
  if constexpr (D == 7) {
    const int4 r = nd7[n - 127];               // ds_read_b128 broadcast
    const float x2 = xT[(r.y << 6) + row];
    const float e = fexp2(__int_as_float(r.x) - x2);
    const float a = frcp(1.0f + e);
    const float pr = p * a;
    const float pl = pr * e;
    unsafeAtomicAdd(&acc[(r.z << 6) + row], pl);  // native ds_add_f32, no rtn
    unsafeAtomicAdd(&acc[(r.w << 6) + row], pr);
  } else {
    float pl, pr;
    evaln(nd, xT, n, row, p, pl, pr);
    dfs<D + 1>(nd, nd7, xT, acc, 2 * n + 1, row, pl);
    dfs<D + 1>(nd, nd7, xT, acc, 2 * n + 2, row, pr);
  }
}

__global__ __launch_bounds__(TPB, 8)
void dt_kernel(const float* __restrict__ x,
               const float* __restrict__ thr,
               const int*   __restrict__ feats,
               const int*   __restrict__ leafc,
               float*       __restrict__ out) {
  __shared__ int2  s_nd[127];          // depths 0..6: {t*log2e bits, feat}
  __shared__ int4  s_nd7[128];         // depth 7: {t*log2e bits, feat, lcL, lcR}
  __shared__ float s_xT[NFEAT * RPB];  // transposed, pre-scaled by log2e
  __shared__ float s_acc[NCLS * RPB];  // class accumulators, row-indexed

  const int t   = threadIdx.x;
  const int row = t & (RPB - 1);
  const int h   = t >> 6;              // wave-uniform: which pair of subtrees

  // --- stage node params (once) ---
  if (t < 127) {
    s_nd[t] = make_int2(__float_as_int(thr[t] * L2E), feats[t]);
  } else if (t < 255) {
    const int n7 = t - 127;
    s_nd7[n7] = make_int4(__float_as_int(thr[t] * L2E), feats[t],
                          leafc[2 * n7], leafc[2 * n7 + 1]);
  }

  // --- stage x: coalesced float4 reads, transposed LDS writes ---
  const float4* xg = (const float4*)x + (size_t)blockIdx.x * (RPB * NFEAT / 4);
#pragma unroll
  for (int k = 0; k < 2; ++k) {
    const int i4 = k * TPB + t;                // 0..511
    const float4 v = xg[i4];
    const int r  = i4 >> 3;                    // local row
    const int c0 = (i4 & 7) * 4;               // first of 4 feature columns
    s_xT[(c0 + 0) * RPB + r] = v.x * L2E;
    s_xT[(c0 + 1) * RPB + r] = v.y * L2E;
    s_xT[(c0 + 2) * RPB + r] = v.z * L2E;
    s_xT[(c0 + 3) * RPB + r] = v.w * L2E;
  }

  // --- zero accumulators ---
#pragma unroll
  for (int k = 0; k < NCLS; ++k)
    if (k * TPB + t < NCLS * RPB) ;            // (layout is 2560 = 10*256)
#pragma unroll
  for (int k = 0; k < NCLS * RPB / TPB + 1; ++k) {
    const int j = k * TPB + t;
    if (j < NCLS * RPB) s_acc[j] = 0.0f;
  }

  __syncthreads();

  // --- top of tree: 3 evals give this thread's 2 depth-3 subtree probs ---
  float pl, pr;
  evaln(s_nd, s_xT, 0, row, 1.0f, pl, pr);
  const float pd1 = (h >> 1) ? pr : pl;        // prob of node 1+(h>>1)
  evaln(s_nd, s_xT, 1 + (h >> 1), row, pd1, pl, pr);
  const float pd2 = (h & 1) ? pr : pl;         // prob of node 3+h
  evaln(s_nd, s_xT, 3 + h, row, pd2, pl, pr);  // probs of nodes 7+2h, 8+2h

  // --- 2 depth-3..7 subtrees (15 b64-evals + 16 b128 leaf-pairs each) ---
  const int mb = 7 + 2 * h;
  const float ps0 = pl, ps1 = pr;
#pragma unroll 1
  for (int s = 0; s < 2; ++s) {
    dfs<3>(s_nd, s_nd7, s_xT, s_acc, mb + s, row, s ? ps1 : ps0);
  }

  __syncthreads();                             // drain ds_adds

  // --- coalesced output write ---
  float* og = out + (size_t)blockIdx.x * (RPB * NCLS);
#pragma unroll
  for (int k = 0; k < 3; ++k) {
    const int j = k * TPB + t;                 // 0..767, need < 640
    if (j < RPB * NCLS) {
      const int r = j / NCLS;                  // magic-mul
      const int c = j - r * NCLS;
      og[j] = s_acc[(c << 6) + r];
    }
  }
}

extern "C" void kernel_launch(void* const* d_in, const int* in_sizes, int n_in,
                              void* d_out, int out_size, void* d_ws, size_t ws_size,
                              hipStream_t stream) {
  const float* x     = (const float*)d_in[0];
  const float* thr   = (const float*)d_in[1];
  const int*   feats = (const int*)d_in[2];
  const int*   leafc = (const int*)d_in[3];
  float*       out   = (float*)d_out;

  const int B    = in_sizes[0] / NFEAT;        // 131072
  const int grid = B / RPB;                    // 2048

  dt_kernel<<<grid, TPB, 0, stream>>>(x, thr, feats, leafc, out);
}

// Round 6
// 90.190 us; speedup vs baseline: 2.6764x; 2.6764x over previous
//
#include <hip/hip_runtime.h>

// Soft decision tree DEPTH=8, 255 internal nodes (heap order), 256 leaves,
// 10 classes, B=131072, 32 feats. fp32 in/out.
//
// R6: eliminate ALL LDS read-modify-write from the hot loop.
// Measured: LDS fp32 atomics (CAS R1/R2 or native ds_add_f32 R5) = 183us;
// plain LDS RMW chains (R4) = 86us; both are DS-serialization plateaus.
// New structure:
//  - Per block: sort 256 leaves by (pass, class) once using native integer
//    ds_add_rtn_u32 on 20 counters; leaf -> slot (pass-relative 0..127).
//    Slots baked into depth-7 records {thr, feat, slotL, slotR}.
//  - Hot loop per leaf-pair: eval + 2 pure ds_write_b32 into
//    leafp[slot*64 + row] (write-only, no chains; bank = row%32, conflict-free).
//  - Epilogue per (class,row): sum the class's CONTIGUOUS slot range,
//    4-way unrolled independent reads into register partials.
//    Wave-uniform class (c = h + 4k) -> broadcast base/cnt, lane-linear reads.
//  - Two passes (leaf halves by depth-3 subtree parity) halve leafp to 32 KB:
//    static LDS 45.3 KB -> 3 blocks/CU, no dynamic-LDS harness risk.
//  - 4 threads/row (h = t>>6 owns 2 depth-3 subtrees, one per pass).
// LDS = 32768 (leafp) + 8192 (xT) + 1016 (nd) + 2048 (nd7) + 1024 (sp)
//       + 256 (cnt/base) = 45304 B.

#define NFEAT 32
#define NCLS  10
#define TPB   256
#define RPB   64           // rows per block (4 threads per row)
#define L2E   1.4426950408889634f

__device__ __forceinline__ float fexp2(float z) {
#if __has_builtin(__builtin_amdgcn_exp2f)
  return __builtin_amdgcn_exp2f(z);
#else
  return exp2f(z);
#endif
}
__device__ __forceinline__ float frcp(float z) {
#if __has_builtin(__builtin_amdgcn_rcpf)
  return __builtin_amdgcn_rcpf(z);
#else
  return 1.0f / z;
#endif
}

// sigmoid(x-t): e = exp2(t2 - x2); act = 1/(1+e); 1-act = e*act
__device__ __forceinline__ void evaln(const int2* nd, const float* xT,
                                      int n, int row, float p,
                                      float& pl, float& pr) {
  const int2 r = nd[n];                        // ds_read_b64 broadcast
  const float x2 = xT[(r.y << 6) + row];       // ds_read_b32 lane-linear
  const float e = fexp2(__int_as_float(r.x) - x2);
  const float a = frcp(1.0f + e);
  pr = p * a;
  pl = pr * e;
}

template <int D>
__device__ __forceinline__ void dfs(const int2* nd, const int4* nd7,
                                    const float* xT, float* lp,
                                    int n, int row, float p) {
  if constexpr (D == 7) {
    const int4 r = nd7[n - 127];               // {t2, feat, slotL, slotR}
    const float x2 = xT[(r.y << 6) + row];
    const float e = fexp2(__int_as_float(r.x) - x2);
    const float a = frcp(1.0f + e);
    const float pr = p * a;
    const float pl = pr * e;
    lp[(r.z << 6) + row] = pl;                 // pure ds_write_b32, no chain
    lp[(r.w << 6) + row] = pr;
  } else {
    float pl, pr;
    evaln(nd, xT, n, row, p, pl, pr);
    dfs<D + 1>(nd, nd7, xT, lp, 2 * n + 1, row, pl);
    dfs<D + 1>(nd, nd7, xT, lp, 2 * n + 2, row, pr);
  }
}

__global__ __launch_bounds__(TPB, 3)
void dt_kernel(const float* __restrict__ x,
               const float* __restrict__ thr,
               const int*   __restrict__ feats,
               const int*   __restrict__ leafc,
               float*       __restrict__ out) {
  __shared__ float    s_leafp[128 * RPB];   // 32 KB, slot-major [slot*64+row]
  __shared__ float    s_xT[NFEAT * RPB];    // 8 KB, transposed, *log2e
  __shared__ int2     s_nd[127];            // depths 0..6 {t2, feat}
  __shared__ int4     s_nd7[128];           // depth 7 {t2, feat, slotL, slotR}
  __shared__ int      s_sp[256];            // leaf -> pass-relative slot
  __shared__ unsigned s_cnt[2][16];         // per (pass, class) count
  __shared__ unsigned s_base[2][16];        // per (pass, class) base

  const int t   = threadIdx.x;
  const int row = t & (RPB - 1);
  const int h   = t >> 6;                   // wave-uniform subtree-pair id

  // --- stage x: coalesced float4 reads, transposed LDS writes ---
  const float4* xg = (const float4*)x + (size_t)blockIdx.x * (RPB * NFEAT / 4);
#pragma unroll
  for (int k = 0; k < 2; ++k) {
    const int i4 = k * TPB + t;              // 0..511
    const float4 v = xg[i4];
    const int r  = i4 >> 3;
    const int c0 = (i4 & 7) * 4;
    s_xT[(c0 + 0) * RPB + r] = v.x * L2E;
    s_xT[(c0 + 1) * RPB + r] = v.y * L2E;
    s_xT[(c0 + 2) * RPB + r] = v.z * L2E;
    s_xT[(c0 + 3) * RPB + r] = v.w * L2E;
  }
  // --- stage depth 0..6 node records ---
  if (t < 127) s_nd[t] = make_int2(__float_as_int(thr[t] * L2E), feats[t]);
  // --- zero sort counters ---
  if (t < 32) s_cnt[t >> 4][t & 15] = 0u;
  // --- my leaf's class (coalesced global read) ---
  const int myc = leafc[t];                  // leaf index == t (0..255)
  const int myP = (t >> 5) & 1;              // pass = depth-3 subtree parity

  __syncthreads();                           // B1: counters zeroed

  const unsigned pos = atomicAdd(&s_cnt[myP][myc], 1u);  // ds_add_rtn_u32

  __syncthreads();                           // B2: counts final

  if (t < 2) {                               // prefix-sum per pass
    unsigned b = 0;
#pragma unroll
    for (int c = 0; c < NCLS; ++c) { s_base[t][c] = b; b += s_cnt[t][c]; }
  }

  __syncthreads();                           // B3: bases ready

  s_sp[t] = (int)(s_base[myP][myc] + pos);   // leaf -> slot (0..127 per pass)

  __syncthreads();                           // B4: slots ready

  if (t < 128) {                             // depth-7 records w/ baked slots
    s_nd7[t] = make_int4(__float_as_int(thr[127 + t] * L2E), feats[127 + t],
                         s_sp[2 * t], s_sp[2 * t + 1]);
  }

  __syncthreads();                           // B5: all staged

  // --- top of tree: 3 evals -> this thread's 2 depth-3 subtree probs ---
  float pl, pr;
  evaln(s_nd, s_xT, 0, row, 1.0f, pl, pr);
  const float pd1 = (h >> 1) ? pr : pl;
  evaln(s_nd, s_xT, 1 + (h >> 1), row, pd1, pl, pr);
  const float pd2 = (h & 1) ? pr : pl;
  evaln(s_nd, s_xT, 3 + h, row, pd2, pl, pr);
  const float ps0 = pl, ps1 = pr;            // subtrees 7+2h (pass0), 8+2h (pass1)
  const int mb = 7 + 2 * h;

  float acc0 = 0.0f, acc1 = 0.0f, acc2 = 0.0f;

#pragma unroll 1
  for (int pass = 0; pass < 2; ++pass) {
    // --- compute: one depth-3..7 subtree, write-only leaf probs ---
    dfs<3>(s_nd, s_nd7, s_xT, s_leafp, mb + pass, row, pass ? ps1 : ps0);

    __syncthreads();                         // leafp complete for this pass

    // --- epilogue: per wave-uniform class, sum contiguous slot range ---
#pragma unroll
    for (int k = 0; k < 3; ++k) {
      const int c = h + 4 * k;
      if (c < NCLS) {
        const int s0 = __builtin_amdgcn_readfirstlane((int)s_base[pass][c]);
        const int n  = __builtin_amdgcn_readfirstlane((int)s_cnt[pass][c]);
        float a0 = 0.f, a1 = 0.f, a2 = 0.f, a3 = 0.f;
        int i = 0;
        for (; i + 4 <= n; i += 4) {         // 4 independent reads in flight
          a0 += s_leafp[((s0 + i + 0) << 6) + row];
          a1 += s_leafp[((s0 + i + 1) << 6) + row];
          a2 += s_leafp[((s0 + i + 2) << 6) + row];
          a3 += s_leafp[((s0 + i + 3) << 6) + row];
        }
        for (; i < n; ++i) a0 += s_leafp[((s0 + i) << 6) + row];
        const float a = (a0 + a1) + (a2 + a3);
        if (k == 0) acc0 += a; else if (k == 1) acc1 += a; else acc2 += a;
      }
    }

    __syncthreads();                         // epilogue reads done before pass B
  }

  // --- output: each thread writes its 2-3 (row, class) results ---
  float* og = out + (size_t)blockIdx.x * (RPB * NCLS);
  og[row * NCLS + h] = acc0;
  og[row * NCLS + h + 4] = acc1;
  if (h < 2) og[row * NCLS + h + 8] = acc2;
}

extern "C" void kernel_launch(void* const* d_in, const int* in_sizes, int n_in,
                              void* d_out, int out_size, void* d_ws, size_t ws_size,
                              hipStream_t stream) {
  const float* x     = (const float*)d_in[0];
  const float* thr   = (const float*)d_in[1];
  const int*   feats = (const int*)d_in[2];
  const int*   leafc = (const int*)d_in[3];
  float*       out   = (float*)d_out;

  const int B    = in_sizes[0] / NFEAT;      // 131072
  const int grid = B / RPB;                  // 2048

  dt_kernel<<<grid, TPB, 0, stream>>>(x, thr, feats, leafc, out);
}